// Round 1
// baseline (227.589 us; speedup 1.0000x reference)
//
#include <hip/hip_runtime.h>

// YOLO loss forward on MI355X.
// input/target: (B=256, C=25, S=64, S=64) fp32, row-major.
// Memory-bound reduction: 209.7 MB -> 1 float. Roofline ~33 us at 6.3 TB/s.
//
// V2: split work by channel role to maximize memory-level parallelism.
//  - class part: one item per (channel 5..24, float4-group); 3 independent
//    coalesced loads per item (p_c, t_c, t4 mask). t4 re-reads are L2/L3-hot.
//  - box part: channels 0..4 math (coord/iou/conf), 10 loads per thread.
// Previous version: 1 thread = 50 serialized loads at VGPR=32 -> latency-bound
// (VALUBusy 7%, HBM 16%, occupancy 34%).

#define COORD 5.0f
#define NOOBJ 0.5f

constexpr int B = 256;
constexpr int C = 25;
constexpr int S = 64;
constexpr int SS = S * S;                    // 4096 spatial positions per image
constexpr int CH_STRIDE4 = SS / 4;           // 1024 float4 per channel plane
constexpr int IMG_STRIDE4 = C * CH_STRIDE4;  // 25600 float4 per image
constexpr int N4 = B * SS / 4;               // 262144 float4-groups (= 2^18)

constexpr int THREADS = 256;
constexpr int CLASS_CH = 20;                          // channels 5..24
constexpr int CLASS_ITEMS = CLASS_CH * N4;            // 5,242,880
constexpr int CLASS_BLOCKS = 2560;
constexpr int CLASS_THREADS = CLASS_BLOCKS * THREADS; // 655,360
constexpr int CLASS_IPT = CLASS_ITEMS / CLASS_THREADS; // 8 items/thread
constexpr int BOX_BLOCKS = N4 / THREADS;              // 1024
constexpr int TOTAL_BLOCKS = CLASS_BLOCKS + BOX_BLOCKS; // 3584

__device__ __forceinline__ float comp(const float4 v, int k) {
    switch (k) {
        case 0: return v.x;
        case 1: return v.y;
        case 2: return v.z;
        default: return v.w;
    }
}

__global__ void zero_out_kernel(float* out) { out[0] = 0.0f; }

__global__ __launch_bounds__(256) void yolo_loss_kernel(
        const float4* __restrict__ in, const float4* __restrict__ tg,
        float* __restrict__ out) {
    float acc = 0.0f;

    if (blockIdx.x < CLASS_BLOCKS) {
        // ---- class terms: sum_m m * (p_c - t_c)^2 over channels 5..24 ----
        const int t = blockIdx.x * THREADS + threadIdx.x;
        #pragma unroll
        for (int i = 0; i < CLASS_IPT; i += 2) {
            const int it0 = t + (i + 0) * CLASS_THREADS;
            const int it1 = t + (i + 1) * CLASS_THREADS;
            // item -> (channel, group). N4 = 2^18.
            const int c0 = 5 + (it0 >> 18);
            const int c1 = 5 + (it1 >> 18);
            const int g0 = it0 & (N4 - 1);
            const int g1 = it1 & (N4 - 1);
            const int base0 = (g0 >> 10) * IMG_STRIDE4 + (g0 & 1023);
            const int base1 = (g1 >> 10) * IMG_STRIDE4 + (g1 & 1023);
            // 6 independent loads in flight per batch
            const float4 pv0 = in[base0 + c0 * CH_STRIDE4];
            const float4 tv0 = tg[base0 + c0 * CH_STRIDE4];
            const float4 mk0 = tg[base0 + 4 * CH_STRIDE4];
            const float4 pv1 = in[base1 + c1 * CH_STRIDE4];
            const float4 tv1 = tg[base1 + c1 * CH_STRIDE4];
            const float4 mk1 = tg[base1 + 4 * CH_STRIDE4];
            float d;
            d = pv0.x - tv0.x; acc += (mk0.x > 0.0f) ? d * d : 0.0f;
            d = pv0.y - tv0.y; acc += (mk0.y > 0.0f) ? d * d : 0.0f;
            d = pv0.z - tv0.z; acc += (mk0.z > 0.0f) ? d * d : 0.0f;
            d = pv0.w - tv0.w; acc += (mk0.w > 0.0f) ? d * d : 0.0f;
            d = pv1.x - tv1.x; acc += (mk1.x > 0.0f) ? d * d : 0.0f;
            d = pv1.y - tv1.y; acc += (mk1.y > 0.0f) ? d * d : 0.0f;
            d = pv1.z - tv1.z; acc += (mk1.z > 0.0f) ? d * d : 0.0f;
            d = pv1.w - tv1.w; acc += (mk1.w > 0.0f) ? d * d : 0.0f;
        }
    } else {
        // ---- box terms: channels 0..4 (coord + iou + conf + noobj) ----
        const int g = (blockIdx.x - CLASS_BLOCKS) * THREADS + threadIdx.x; // < N4
        const int base = (g >> 10) * IMG_STRIDE4 + (g & 1023);

        // 10 independent loads in flight
        const float4 p0 = in[base + 0 * CH_STRIDE4];
        const float4 p1 = in[base + 1 * CH_STRIDE4];
        const float4 p2 = in[base + 2 * CH_STRIDE4];
        const float4 p3 = in[base + 3 * CH_STRIDE4];
        const float4 p4 = in[base + 4 * CH_STRIDE4];
        const float4 t0 = tg[base + 0 * CH_STRIDE4];
        const float4 t1 = tg[base + 1 * CH_STRIDE4];
        const float4 t2 = tg[base + 2 * CH_STRIDE4];
        const float4 t3 = tg[base + 3 * CH_STRIDE4];
        const float4 t4 = tg[base + 4 * CH_STRIDE4];

        const float invBlocks = 1.0f / (float)S;
        #pragma unroll
        for (int k = 0; k < 4; ++k) {
            const float px = comp(p0, k), py = comp(p1, k);
            const float pw = comp(p2, k), ph = comp(p3, k);
            const float pc = comp(p4, k);
            const float tx = comp(t0, k), ty = comp(t1, k);
            const float tw = comp(t2, k), th = comp(t3, k);
            const float tc = comp(t4, k);
            const float m = (tc > 0.0f) ? 1.0f : 0.0f;

            // IoU (forward values only)
            const float c1x = px * invBlocks, c1y = py * invBlocks;
            const float c2x = tx * invBlocks, c2y = ty * invBlocks;
            const float x1a = c1x - pw * 0.5f, x2a = c1x + pw * 0.5f;
            const float y1a = c1y - ph * 0.5f, y2a = c1y + ph * 0.5f;
            const float x1b = c2x - tw * 0.5f, x2b = c2x + tw * 0.5f;
            const float y1b = c2y - th * 0.5f, y2b = c2y + th * 0.5f;
            const float dx = fminf(x2a, x2b) - fmaxf(x1a, x1b);
            const float dy = fminf(y2a, y2b) - fmaxf(y1a, y1b);
            const float inter = dx * dy;
            const float uni = pw * ph + tw * th - inter;
            const bool pos = (dx > 0.0f) && (dy > 0.0f);
            const float iou = pos ? (inter / uni) : 0.0f;

            // coord terms
            const float ex = px - tx, ey = py - ty;
            acc += COORD * m * (ex * ex + ey * ey);
            const float sw = sqrtf(pw) - sqrtf(tw);
            const float sh = sqrtf(ph) - sqrtf(th);
            acc += COORD * m * (sw * sw + sh * sh);
            // confidence terms
            const float ec = pc - iou;
            acc += m * ec * ec;
            acc += NOOBJ * (1.0f - m) * (pc * pc);
        }
    }

    // wave64 reduce
    #pragma unroll
    for (int off = 32; off > 0; off >>= 1)
        acc += __shfl_down(acc, off, 64);

    __shared__ float smem[4];
    const int lane = threadIdx.x & 63;
    const int wid = threadIdx.x >> 6;
    if (lane == 0) smem[wid] = acc;
    __syncthreads();
    if (threadIdx.x == 0) {
        const float s = smem[0] + smem[1] + smem[2] + smem[3];
        atomicAdd(out, s);
    }
}

extern "C" void kernel_launch(void* const* d_in, const int* in_sizes, int n_in,
                              void* d_out, int out_size, void* d_ws, size_t ws_size,
                              hipStream_t stream) {
    const float4* in = (const float4*)d_in[0];
    const float4* tg = (const float4*)d_in[1];
    float* out = (float*)d_out;

    // d_out is re-poisoned to 0xAA before every timed launch -> zero it first.
    zero_out_kernel<<<1, 1, 0, stream>>>(out);

    yolo_loss_kernel<<<TOTAL_BLOCKS, THREADS, 0, stream>>>(in, tg, out);
}